// Round 8
// baseline (312.891 us; speedup 1.0000x reference)
//
#include <hip/hip_runtime.h>

// H2G2: 2-layer RGCN (R=4, per-relation mean) + mean-pool + linear.
// R1->R2: atomic scatter -> CSR gather. R2->R3: atomic pool -> segmented pool+cls.
// R3->R4: fp32 LDS GEMM -> bf16 MFMA. R4->R5: CSR via 2-level bucket sort.
// R5->R6/7: aggregate-then-transform; K=320 MFMA GEMM fuses [root|W0..3]+bias+relu.
// R7->R8: fuse agg+gemm into layer_kernel. Each wave aggregates the 16 nodes
// whose GEMM rows it owns, Y lives in LDS (stride 264 = 2-way-free banks),
// killing the 51.2MB/layer Y global round-trip + 1 dispatch/layer. tmp packed
// int2->int (src:16|et:2|dl:8). Requires N <= 65536 (N=50000).

#define RR 4
#define HH 64
#define KK 320         // (RR+1)*HH
#define LWN (HH * KK)  // weights per layer = 20480
#define EPB 4096       // edges per binning block
#define SBUF_D 6144    // per-bucket staging cap
#define YSTRIDE 264    // 256 + 8 pad (shorts): phase-2 b128 reads 2-way only

using frag_ab = __attribute__((ext_vector_type(8))) short;
using frag_cd = __attribute__((ext_vector_type(4))) float;

__device__ inline short f2bf(float f) {
    unsigned u = __builtin_bit_cast(unsigned, f);
    unsigned r = u + 0x7fffu + ((u >> 16) & 1u);  // RNE
    return (short)(r >> 16);
}
__device__ inline float bf2f(short s) {
    unsigned u = ((unsigned)(unsigned short)s) << 16;
    return __builtin_bit_cast(float, u);
}

// ---- prep: fused init-independent work, partitioned by blockIdx ----
__global__ __launch_bounds__(256) void prep_kernel(
    const int* __restrict__ dst, int E, int NBUCK, int* __restrict__ bcnt,
    const float* __restrict__ basis1, const float* __restrict__ comp1, const float* __restrict__ root1,
    const float* __restrict__ basis2, const float* __restrict__ comp2, const float* __restrict__ root2,
    short* __restrict__ W1t, short* __restrict__ W2t,
    const int* __restrict__ batch, int* __restrict__ gstart, int N, int G,
    int* __restrict__ row_ptr,
    const float* __restrict__ x, short* __restrict__ Xb,
    int ebl, int wbl, int nb) {
    const int bid = blockIdx.x;
    const int t = threadIdx.x;
    if (bid < ebl) {  // ---- histogram of dst>>8 ----
        __shared__ int lc[256];
        lc[t] = 0;
        __syncthreads();
        int e0 = bid * EPB, e1 = min(e0 + EPB, E);
        for (int e = e0 + t; e < e1; e += 256) atomicAdd(&lc[dst[e] >> 8], 1);
        __syncthreads();
        if (t < NBUCK && lc[t]) atomicAdd(&bcnt[t], lc[t]);
    } else if (bid < ebl + wbl) {  // ---- weights: Wt[c*320+k] = Wstack[k][c] ----
        int w = (bid - ebl) * 256 + t;
        int layer = w / LWN;
        int rem = w - layer * LWN;
        int c = rem / KK;
        int k = rem - c * KK;
        const float* basis = layer ? basis2 : basis1;
        const float* comp  = layer ? comp2  : comp1;
        const float* root  = layer ? root2  : root1;
        short* Wt          = layer ? W2t    : W1t;
        float v;
        if (k < HH) {
            v = root[k * HH + c];
        } else {
            int r = (k >> 6) - 1, kk = k & 63;
            v = 0.f;
#pragma unroll
            for (int b = 0; b < RR; ++b) v += comp[r * RR + b] * basis[(b * HH + kk) * HH + c];
        }
        Wt[c * KK + k] = f2bf(v);
    } else if (bid < ebl + wbl + nb) {  // ---- gstart + row_ptr sentinel ----
        int i = (bid - ebl - wbl) * 256 + t;
        if (i == 0) row_ptr[N] = E;
        if (i < N) {
            int b1 = batch[i];
            int b0 = (i == 0) ? -1 : batch[i - 1];
            for (int g = b0 + 1; g <= b1; ++g) gstart[g] = i;
            if (i == N - 1)
                for (int g = b1 + 1; g <= G; ++g) gstart[g] = N;
        }
    } else {  // ---- convert x fp32 -> bf16 ----
        int i4 = (bid - ebl - wbl - nb) * 256 + t;
        int base = i4 * 4;
        if (base < N * 64) {
            float4 f = *(const float4*)&x[base];
            short4 s;
            s.x = f2bf(f.x); s.y = f2bf(f.y); s.z = f2bf(f.z); s.w = f2bf(f.w);
            *(short4*)&Xb[base] = s;
        }
    }
}

// ---- bin: block-local counting sort by bucket; packed payload src:16|et:2|dl:8 ----
__global__ __launch_bounds__(256) void bin_kernel(const int* __restrict__ src,
                                                  const int* __restrict__ dst,
                                                  const int* __restrict__ et,
                                                  const int* __restrict__ bcnt,
                                                  int* __restrict__ cur0,
                                                  int* __restrict__ tmp, int E) {
    __shared__ int lc[256];
    __shared__ int lscan[257];
    __shared__ int lbase[256];
    __shared__ int ss[256];
    __shared__ int sbuf[EPB];
    int t = threadIdx.x;
    int bv = bcnt[t];
    ss[t] = bv;
    __syncthreads();
#pragma unroll
    for (int off = 1; off < 256; off <<= 1) {
        int u = (t >= off) ? ss[t - off] : 0;
        __syncthreads();
        ss[t] += u;
        __syncthreads();
    }
    int boff_t = ss[t] - bv;
    lc[t] = 0;
    __syncthreads();
    int e0 = blockIdx.x * EPB;
    int e1 = min(e0 + EPB, E);
    for (int e = e0 + t; e < e1; e += 256) atomicAdd(&lc[dst[e] >> 8], 1);
    __syncthreads();
    int v = lc[t];
    ss[t] = v;
    __syncthreads();
#pragma unroll
    for (int off = 1; off < 256; off <<= 1) {
        int u = (t >= off) ? ss[t - off] : 0;
        __syncthreads();
        ss[t] += u;
        __syncthreads();
    }
    lscan[t] = ss[t] - v;
    if (t == 255) lscan[256] = ss[255];
    if (v) lbase[t] = boff_t + atomicAdd(&cur0[t], v);
    lc[t] = 0;
    __syncthreads();
    for (int e = e0 + t; e < e1; e += 256) {
        int d = dst[e];
        int b = d >> 8;
        int p = (src[e] << 10) | (et[e] << 8) | (d & 255);
        int pos = lscan[b] + atomicAdd(&lc[b], 1);
        sbuf[pos] = p;
    }
    __syncthreads();
    int tot = lscan[256];
    for (int i = t; i < tot; i += 256) {
        int lo = 0, hi = 255;
        while (lo < hi) { int mid = (lo + hi + 1) >> 1; if (lscan[mid] <= i) lo = mid; else hi = mid - 1; }
        tmp[lbase[lo] + (i - lscan[lo])] = sbuf[i];
    }
}

// ---- csr: per-bucket finalize: row_ptr, inv, locally-sorted eidx ----
__global__ __launch_bounds__(256) void csr_kernel(const int* __restrict__ tmp,
                                                  const int* __restrict__ bcnt,
                                                  int* __restrict__ row_ptr,
                                                  int* __restrict__ eidx,
                                                  float* __restrict__ inv, int N) {
    __shared__ int cnt4l[1024];
    __shared__ int dscan[256];
    __shared__ int ss[256];
    __shared__ int dcur[256];
    __shared__ int sb[SBUF_D];
    int b = blockIdx.x, t = threadIdx.x;
    int bv = bcnt[t];
    ss[t] = bv;
    __syncthreads();
#pragma unroll
    for (int off = 1; off < 256; off <<= 1) {
        int u = (t >= off) ? ss[t - off] : 0;
        __syncthreads();
        ss[t] += u;
        __syncthreads();
    }
    __shared__ int s0s, s1s;
    if (t == b) { s0s = ss[t] - bv; s1s = ss[t]; }
    __syncthreads();
    int s0 = s0s, s1 = s1s;
    int len = s1 - s0;
    for (int i = t; i < 1024; i += 256) cnt4l[i] = 0;
    __syncthreads();
    for (int i = s0 + t; i < s1; i += 256) {
        int e = tmp[i];
        atomicAdd(&cnt4l[((e & 255) << 2) | ((e >> 8) & 3)], 1);
    }
    __syncthreads();
    int deg = cnt4l[t * 4] + cnt4l[t * 4 + 1] + cnt4l[t * 4 + 2] + cnt4l[t * 4 + 3];
    ss[t] = deg;
    __syncthreads();
#pragma unroll
    for (int off = 1; off < 256; off <<= 1) {
        int u = (t >= off) ? ss[t - off] : 0;
        __syncthreads();
        ss[t] += u;
        __syncthreads();
    }
    dscan[t] = ss[t] - deg;
    dcur[t] = 0;
    int d0 = b << 8;
    if (d0 + t < N) row_ptr[d0 + t] = s0 + dscan[t];
    __syncthreads();
    for (int i = t; i < 1024; i += 256) {
        int d = d0 + (i >> 2);
        if (d < N) inv[d * 4 + (i & 3)] = 1.0f / fmaxf((float)cnt4l[i], 1.0f);
    }
    if (len <= SBUF_D) {
        for (int i = s0 + t; i < s1; i += 256) {
            int e = tmp[i];
            int dl = e & 255;
            int r = (e >> 8) & 3;
            int pos = dscan[dl] + atomicAdd(&dcur[dl], 1);
            sb[pos] = ((e >> 10) << 2) | r;  // (src<<2)|et
        }
        __syncthreads();
        for (int i = t; i < len; i += 256) eidx[s0 + i] = sb[i];
    } else {
        for (int i = s0 + t; i < s1; i += 256) {
            int e = tmp[i];
            int dl = e & 255;
            int r = (e >> 8) & 3;
            int pos = dscan[dl] + atomicAdd(&dcur[dl], 1);
            eidx[s0 + pos] = ((e >> 10) << 2) | r;
        }
    }
}

// ---- fused layer: phase1 per-wave CSR gather -> Y in LDS; phase2 K=320 MFMA ----
// out[n,:] = relu([Xb[n] | Y[n]] @ Wstack + bias), bf16 out.
__global__ __launch_bounds__(256) void layer_kernel(const int* __restrict__ row_ptr,
                                                    const int* __restrict__ eidx,
                                                    const short* __restrict__ Xb,
                                                    const float* __restrict__ inv,
                                                    const short* __restrict__ Wt,  // [c*320+k]
                                                    const float* __restrict__ bias,
                                                    short* __restrict__ out, int n) {
    __shared__ short sY[4][16 * YSTRIDE];  // 33792 B
    const int t = threadIdx.x;
    const int wv = t >> 6;
    const int l = t & 63;
    const int m = l & 15;
    const int quad = l >> 4;
    const int nbase = blockIdx.x * 64 + wv * 16;
    short* myY = sY[wv];

    // phase 1: aggregate this wave's 16 nodes (lane = channel)
    for (int i = 0; i < 16; ++i) {
        int node = nbase + i;
        if (node >= n) break;
        float a0 = 0.f, a1 = 0.f, a2 = 0.f, a3 = 0.f;
        int k = row_ptr[node];
        const int end = row_ptr[node + 1];
#define ACCUM(p, v) { int r = (p) & 3; \
        a0 += (r == 0) ? (v) : 0.f; a1 += (r == 1) ? (v) : 0.f; \
        a2 += (r == 2) ? (v) : 0.f; a3 += (r == 3) ? (v) : 0.f; }
        for (; k + 3 < end; k += 4) {
            int p0 = eidx[k], p1 = eidx[k + 1], p2 = eidx[k + 2], p3 = eidx[k + 3];
            float v0 = bf2f(Xb[(size_t)(p0 >> 2) * 64 + l]);
            float v1 = bf2f(Xb[(size_t)(p1 >> 2) * 64 + l]);
            float v2 = bf2f(Xb[(size_t)(p2 >> 2) * 64 + l]);
            float v3 = bf2f(Xb[(size_t)(p3 >> 2) * 64 + l]);
            ACCUM(p0, v0) ACCUM(p1, v1) ACCUM(p2, v2) ACCUM(p3, v3)
        }
        for (; k < end; ++k) {
            int p = eidx[k];
            float v = bf2f(Xb[(size_t)(p >> 2) * 64 + l]);
            ACCUM(p, v)
        }
#undef ACCUM
        float4 iv = *(const float4*)&inv[node * 4];
        short* yp = myY + i * YSTRIDE + l;
        yp[0]   = f2bf(a0 * iv.x);
        yp[64]  = f2bf(a1 * iv.y);
        yp[128] = f2bf(a2 * iv.z);
        yp[192] = f2bf(a3 * iv.w);
    }
    __syncthreads();

    // phase 2: MFMA K=320. A-frags: X from global, Y from LDS.
    const int node = nbase + m;
    frag_ab a[10];
#pragma unroll
    for (int f = 0; f < 10; ++f) a[f] = frag_ab{};
    if (node < n) {
        const short* xr = Xb + (size_t)node * 64 + quad * 8;
        a[0] = *(const frag_ab*)xr;
        a[1] = *(const frag_ab*)(xr + 32);
        const short* yr = myY + m * YSTRIDE + quad * 8;
#pragma unroll
        for (int f = 0; f < 8; ++f) a[2 + f] = *(const frag_ab*)(yr + f * 32);
    }

    const int nrow_base = nbase + quad * 4;
#pragma unroll
    for (int ct = 0; ct < 4; ++ct) {
        const short* bp = Wt + (size_t)(ct * 16 + m) * KK + quad * 8;
        frag_cd acc = {0.f, 0.f, 0.f, 0.f};
#pragma unroll
        for (int f = 0; f < 10; ++f) {
            frag_ab bf = *(const frag_ab*)(bp + f * 32);
            acc = __builtin_amdgcn_mfma_f32_16x16x32_bf16(a[f], bf, acc, 0, 0, 0);
        }
        int col = ct * 16 + m;
        float bv = bias[col];
#pragma unroll
        for (int r = 0; r < 4; ++r) {
            int nr = nrow_base + r;
            if (nr < n) out[(size_t)nr * 64 + col] = f2bf(fmaxf(acc[r] + bv, 0.f));
        }
    }
}

// ---- pool (segmented) + classifier ----
__global__ __launch_bounds__(256) void pool_cls_kernel(const short* __restrict__ h2,
                                                       const int* __restrict__ gstart,
                                                       const float* __restrict__ w,
                                                       const float* __restrict__ b,
                                                       float* __restrict__ out) {
    __shared__ float red[4][64];
    const int g = blockIdx.x;
    const int t = threadIdx.x;
    const int h = t & 63;
    const int wv = t >> 6;
    const int s = gstart[g], e = gstart[g + 1];

    float acc = 0.f;
    for (int i = s + wv; i < e; i += 4) acc += bf2f(h2[(size_t)i * 64 + h]);
    red[wv][h] = acc;
    __syncthreads();
    if (wv == 0) {
        float sum = red[0][h] + red[1][h] + red[2][h] + red[3][h];
        red[0][h] = sum / fmaxf((float)(e - s), 1.0f);
    }
    __syncthreads();
    if (t < 4) {
        float sres = 0.f;
#pragma unroll 8
        for (int hh = 0; hh < 64; ++hh) sres += red[0][hh] * w[hh * 4 + t];
        out[g * 4 + t] = sres + b[t];
    }
}

extern "C" void kernel_launch(void* const* d_in, const int* in_sizes, int n_in,
                              void* d_out, int out_size, void* d_ws, size_t ws_size,
                              hipStream_t stream) {
    const float* x        = (const float*)d_in[0];
    const int* edge_index = (const int*)d_in[1];
    const int* edge_type  = (const int*)d_in[2];
    const int* batch      = (const int*)d_in[3];
    const float* basis1 = (const float*)d_in[4];
    const float* comp1  = (const float*)d_in[5];
    const float* root1  = (const float*)d_in[6];
    const float* bias1  = (const float*)d_in[7];
    const float* basis2 = (const float*)d_in[8];
    const float* comp2  = (const float*)d_in[9];
    const float* root2  = (const float*)d_in[10];
    const float* bias2  = (const float*)d_in[11];
    const float* clas_w = (const float*)d_in[12];
    const float* clas_b = (const float*)d_in[13];

    const int N = in_sizes[0] / 64;
    const int E = in_sizes[2];
    const int G = out_size / 4;
    const int* src = edge_index;
    const int* dst = edge_index + E;
    const int NBUCK = (N + 255) >> 8;

    char* base = (char*)d_ws;
    size_t off = 0;
    auto carve = [&](size_t bytes) { void* p = base + off; off = (off + bytes + 15) & ~(size_t)15; return p; };
    int*   bcnt    = (int*)carve(sizeof(int) * 256);
    int*   cur0    = (int*)carve(sizeof(int) * 256);
    int*   row_ptr = (int*)carve(sizeof(int) * ((size_t)N + 1));
    int*   gstart  = (int*)carve(sizeof(int) * ((size_t)G + 1));
    int*   eidx    = (int*)carve(sizeof(int) * (size_t)E);
    int*   tmp     = (int*)carve(sizeof(int) * (size_t)E);
    float* inv     = (float*)carve(sizeof(float) * (size_t)N * RR);
    short* W1t     = (short*)carve(sizeof(short) * LWN);
    short* W2t     = (short*)carve(sizeof(short) * LWN);
    short* Xb1     = (short*)carve(sizeof(short) * (size_t)N * 64);
    short* H1      = (short*)carve(sizeof(short) * (size_t)N * 64);
    short* H2      = (short*)carve(sizeof(short) * (size_t)N * 64);

    const int nb  = (N + 255) / 256;
    const int ebl = (E + EPB - 1) / EPB;
    const int wbl = (2 * LWN + 255) / 256;
    const int cvb = (N * 64 / 4 + 255) / 256;
    const int prep_blocks = ebl + wbl + nb + cvb;

    hipMemsetAsync(bcnt, 0, sizeof(int) * 512, stream);  // bcnt + cur0

    prep_kernel<<<prep_blocks, 256, 0, stream>>>(
        dst, E, NBUCK, bcnt,
        basis1, comp1, root1, basis2, comp2, root2, W1t, W2t,
        batch, gstart, N, G, row_ptr, x, Xb1, ebl, wbl, nb);
    bin_kernel<<<ebl, 256, 0, stream>>>(src, dst, edge_type, bcnt, cur0, tmp, E);
    csr_kernel<<<NBUCK, 256, 0, stream>>>(tmp, bcnt, row_ptr, eidx, inv, N);

    const int layer_blocks = (N + 63) / 64;

    layer_kernel<<<layer_blocks, 256, 0, stream>>>(row_ptr, eidx, Xb1, inv, W1t, bias1, H1, N);
    layer_kernel<<<layer_blocks, 256, 0, stream>>>(row_ptr, eidx, H1, inv, W2t, bias2, H2, N);

    pool_cls_kernel<<<G, 256, 0, stream>>>(H2, gstart, clas_w, clas_b, (float*)d_out);
}

// Round 9
// 239.826 us; speedup vs baseline: 1.3047x; 1.3047x over previous
//
#include <hip/hip_runtime.h>

// H2G2: 2-layer RGCN (R=4, per-relation mean) + mean-pool + linear.
// R1->R2: atomic scatter -> CSR gather. R2->R3: atomic pool -> segmented pool+cls.
// R3->R4: fp32 LDS GEMM -> bf16 MFMA. R4->R5: CSR via 2-level bucket sort.
// R5->R6/7: aggregate-then-transform; K=320 MFMA GEMM fuses [root|W0..3]+bias+relu.
// R8 FAILED: fusing agg+gemm put agg under a 33.8KB LDS roof -> occupancy 28%
//   -> latency-bound gather lost 2x wave count (89us/layer). REVERTED.
// R9 = R7 structure + packed-int bin/csr (from R8) + agg with 8 gathers in
//   flight and scalarized (readfirstlane) row_ptr/eidx loads.

#define RR 4
#define HH 64
#define KK 320         // (RR+1)*HH
#define LWN (HH * KK)  // weights per layer = 20480
#define EPB 4096       // edges per binning block
#define SBUF_D 6144    // per-bucket staging cap

using frag_ab = __attribute__((ext_vector_type(8))) short;
using frag_cd = __attribute__((ext_vector_type(4))) float;

__device__ inline short f2bf(float f) {
    unsigned u = __builtin_bit_cast(unsigned, f);
    unsigned r = u + 0x7fffu + ((u >> 16) & 1u);  // RNE
    return (short)(r >> 16);
}
__device__ inline float bf2f(short s) {
    unsigned u = ((unsigned)(unsigned short)s) << 16;
    return __builtin_bit_cast(float, u);
}

// ---- prep: fused init-independent work, partitioned by blockIdx ----
__global__ __launch_bounds__(256) void prep_kernel(
    const int* __restrict__ dst, int E, int NBUCK, int* __restrict__ bcnt,
    const float* __restrict__ basis1, const float* __restrict__ comp1, const float* __restrict__ root1,
    const float* __restrict__ basis2, const float* __restrict__ comp2, const float* __restrict__ root2,
    short* __restrict__ W1t, short* __restrict__ W2t,
    const int* __restrict__ batch, int* __restrict__ gstart, int N, int G,
    int* __restrict__ row_ptr,
    const float* __restrict__ x, short* __restrict__ Xb,
    int ebl, int wbl, int nb) {
    const int bid = blockIdx.x;
    const int t = threadIdx.x;
    if (bid < ebl) {  // ---- histogram of dst>>8 ----
        __shared__ int lc[256];
        lc[t] = 0;
        __syncthreads();
        int e0 = bid * EPB, e1 = min(e0 + EPB, E);
        for (int e = e0 + t; e < e1; e += 256) atomicAdd(&lc[dst[e] >> 8], 1);
        __syncthreads();
        if (t < NBUCK && lc[t]) atomicAdd(&bcnt[t], lc[t]);
    } else if (bid < ebl + wbl) {  // ---- weights: Wt[c*320+k] = Wstack[k][c] ----
        int w = (bid - ebl) * 256 + t;
        int layer = w / LWN;
        int rem = w - layer * LWN;
        int c = rem / KK;
        int k = rem - c * KK;
        const float* basis = layer ? basis2 : basis1;
        const float* comp  = layer ? comp2  : comp1;
        const float* root  = layer ? root2  : root1;
        short* Wt          = layer ? W2t    : W1t;
        float v;
        if (k < HH) {
            v = root[k * HH + c];
        } else {
            int r = (k >> 6) - 1, kk = k & 63;
            v = 0.f;
#pragma unroll
            for (int b = 0; b < RR; ++b) v += comp[r * RR + b] * basis[(b * HH + kk) * HH + c];
        }
        Wt[c * KK + k] = f2bf(v);
    } else if (bid < ebl + wbl + nb) {  // ---- gstart + row_ptr sentinel ----
        int i = (bid - ebl - wbl) * 256 + t;
        if (i == 0) row_ptr[N] = E;
        if (i < N) {
            int b1 = batch[i];
            int b0 = (i == 0) ? -1 : batch[i - 1];
            for (int g = b0 + 1; g <= b1; ++g) gstart[g] = i;
            if (i == N - 1)
                for (int g = b1 + 1; g <= G; ++g) gstart[g] = N;
        }
    } else {  // ---- convert x fp32 -> bf16 ----
        int i4 = (bid - ebl - wbl - nb) * 256 + t;
        int base = i4 * 4;
        if (base < N * 64) {
            float4 f = *(const float4*)&x[base];
            short4 s;
            s.x = f2bf(f.x); s.y = f2bf(f.y); s.z = f2bf(f.z); s.w = f2bf(f.w);
            *(short4*)&Xb[base] = s;
        }
    }
}

// ---- bin: block-local counting sort by bucket; packed payload src:16|et:2|dl:8 ----
__global__ __launch_bounds__(256) void bin_kernel(const int* __restrict__ src,
                                                  const int* __restrict__ dst,
                                                  const int* __restrict__ et,
                                                  const int* __restrict__ bcnt,
                                                  int* __restrict__ cur0,
                                                  int* __restrict__ tmp, int E) {
    __shared__ int lc[256];
    __shared__ int lscan[257];
    __shared__ int lbase[256];
    __shared__ int ss[256];
    __shared__ int sbuf[EPB];
    int t = threadIdx.x;
    int bv = bcnt[t];
    ss[t] = bv;
    __syncthreads();
#pragma unroll
    for (int off = 1; off < 256; off <<= 1) {
        int u = (t >= off) ? ss[t - off] : 0;
        __syncthreads();
        ss[t] += u;
        __syncthreads();
    }
    int boff_t = ss[t] - bv;
    lc[t] = 0;
    __syncthreads();
    int e0 = blockIdx.x * EPB;
    int e1 = min(e0 + EPB, E);
    for (int e = e0 + t; e < e1; e += 256) atomicAdd(&lc[dst[e] >> 8], 1);
    __syncthreads();
    int v = lc[t];
    ss[t] = v;
    __syncthreads();
#pragma unroll
    for (int off = 1; off < 256; off <<= 1) {
        int u = (t >= off) ? ss[t - off] : 0;
        __syncthreads();
        ss[t] += u;
        __syncthreads();
    }
    lscan[t] = ss[t] - v;
    if (t == 255) lscan[256] = ss[255];
    if (v) lbase[t] = boff_t + atomicAdd(&cur0[t], v);
    lc[t] = 0;
    __syncthreads();
    for (int e = e0 + t; e < e1; e += 256) {
        int d = dst[e];
        int b = d >> 8;
        int p = (src[e] << 10) | (et[e] << 8) | (d & 255);
        int pos = lscan[b] + atomicAdd(&lc[b], 1);
        sbuf[pos] = p;
    }
    __syncthreads();
    int tot = lscan[256];
    for (int i = t; i < tot; i += 256) {
        int lo = 0, hi = 255;
        while (lo < hi) { int mid = (lo + hi + 1) >> 1; if (lscan[mid] <= i) lo = mid; else hi = mid - 1; }
        tmp[lbase[lo] + (i - lscan[lo])] = sbuf[i];
    }
}

// ---- csr: per-bucket finalize: row_ptr, inv, locally-sorted eidx ----
__global__ __launch_bounds__(256) void csr_kernel(const int* __restrict__ tmp,
                                                  const int* __restrict__ bcnt,
                                                  int* __restrict__ row_ptr,
                                                  int* __restrict__ eidx,
                                                  float* __restrict__ inv, int N) {
    __shared__ int cnt4l[1024];
    __shared__ int dscan[256];
    __shared__ int ss[256];
    __shared__ int dcur[256];
    __shared__ int sb[SBUF_D];
    int b = blockIdx.x, t = threadIdx.x;
    int bv = bcnt[t];
    ss[t] = bv;
    __syncthreads();
#pragma unroll
    for (int off = 1; off < 256; off <<= 1) {
        int u = (t >= off) ? ss[t - off] : 0;
        __syncthreads();
        ss[t] += u;
        __syncthreads();
    }
    __shared__ int s0s, s1s;
    if (t == b) { s0s = ss[t] - bv; s1s = ss[t]; }
    __syncthreads();
    int s0 = s0s, s1 = s1s;
    int len = s1 - s0;
    for (int i = t; i < 1024; i += 256) cnt4l[i] = 0;
    __syncthreads();
    for (int i = s0 + t; i < s1; i += 256) {
        int e = tmp[i];
        atomicAdd(&cnt4l[((e & 255) << 2) | ((e >> 8) & 3)], 1);
    }
    __syncthreads();
    int deg = cnt4l[t * 4] + cnt4l[t * 4 + 1] + cnt4l[t * 4 + 2] + cnt4l[t * 4 + 3];
    ss[t] = deg;
    __syncthreads();
#pragma unroll
    for (int off = 1; off < 256; off <<= 1) {
        int u = (t >= off) ? ss[t - off] : 0;
        __syncthreads();
        ss[t] += u;
        __syncthreads();
    }
    dscan[t] = ss[t] - deg;
    dcur[t] = 0;
    int d0 = b << 8;
    if (d0 + t < N) row_ptr[d0 + t] = s0 + dscan[t];
    __syncthreads();
    for (int i = t; i < 1024; i += 256) {
        int d = d0 + (i >> 2);
        if (d < N) inv[d * 4 + (i & 3)] = 1.0f / fmaxf((float)cnt4l[i], 1.0f);
    }
    if (len <= SBUF_D) {
        for (int i = s0 + t; i < s1; i += 256) {
            int e = tmp[i];
            int dl = e & 255;
            int r = (e >> 8) & 3;
            int pos = dscan[dl] + atomicAdd(&dcur[dl], 1);
            sb[pos] = ((e >> 10) << 2) | r;  // (src<<2)|et
        }
        __syncthreads();
        for (int i = t; i < len; i += 256) eidx[s0 + i] = sb[i];
    } else {
        for (int i = s0 + t; i < s1; i += 256) {
            int e = tmp[i];
            int dl = e & 255;
            int r = (e >> 8) & 3;
            int pos = dscan[dl] + atomicAdd(&dcur[dl], 1);
            eidx[s0 + pos] = ((e >> 10) << 2) | r;
        }
    }
}

// ---- agg: one wave per dst; 8 gathers in flight; scalar row_ptr/eidx loads ----
__global__ __launch_bounds__(256) void agg_kernel(const int* __restrict__ row_ptr,
                                                  const int* __restrict__ eidx,
                                                  const short* __restrict__ Xb,
                                                  const float* __restrict__ inv,
                                                  short* __restrict__ Y, int n) {
    const int l = threadIdx.x & 63;
    const int wid = __builtin_amdgcn_readfirstlane(
        (int)((blockIdx.x * 256 + threadIdx.x) >> 6));  // wave-uniform node id
    if (wid >= n) return;

    float a0 = 0.f, a1 = 0.f, a2 = 0.f, a3 = 0.f;
    int k = row_ptr[wid];
    const int end = row_ptr[wid + 1];
#define ACCUM(p, v) { int r = (p) & 3; \
    a0 += (r == 0) ? (v) : 0.f; a1 += (r == 1) ? (v) : 0.f; \
    a2 += (r == 2) ? (v) : 0.f; a3 += (r == 3) ? (v) : 0.f; }
    for (; k + 7 < end; k += 8) {
        int p0 = eidx[k],     p1 = eidx[k + 1], p2 = eidx[k + 2], p3 = eidx[k + 3];
        int p4 = eidx[k + 4], p5 = eidx[k + 5], p6 = eidx[k + 6], p7 = eidx[k + 7];
        float v0 = bf2f(Xb[(size_t)(p0 >> 2) * 64 + l]);
        float v1 = bf2f(Xb[(size_t)(p1 >> 2) * 64 + l]);
        float v2 = bf2f(Xb[(size_t)(p2 >> 2) * 64 + l]);
        float v3 = bf2f(Xb[(size_t)(p3 >> 2) * 64 + l]);
        float v4 = bf2f(Xb[(size_t)(p4 >> 2) * 64 + l]);
        float v5 = bf2f(Xb[(size_t)(p5 >> 2) * 64 + l]);
        float v6 = bf2f(Xb[(size_t)(p6 >> 2) * 64 + l]);
        float v7 = bf2f(Xb[(size_t)(p7 >> 2) * 64 + l]);
        ACCUM(p0, v0) ACCUM(p1, v1) ACCUM(p2, v2) ACCUM(p3, v3)
        ACCUM(p4, v4) ACCUM(p5, v5) ACCUM(p6, v6) ACCUM(p7, v7)
    }
    for (; k + 3 < end; k += 4) {
        int p0 = eidx[k], p1 = eidx[k + 1], p2 = eidx[k + 2], p3 = eidx[k + 3];
        float v0 = bf2f(Xb[(size_t)(p0 >> 2) * 64 + l]);
        float v1 = bf2f(Xb[(size_t)(p1 >> 2) * 64 + l]);
        float v2 = bf2f(Xb[(size_t)(p2 >> 2) * 64 + l]);
        float v3 = bf2f(Xb[(size_t)(p3 >> 2) * 64 + l]);
        ACCUM(p0, v0) ACCUM(p1, v1) ACCUM(p2, v2) ACCUM(p3, v3)
    }
    for (; k < end; ++k) {
        int p = eidx[k];
        float v = bf2f(Xb[(size_t)(p >> 2) * 64 + l]);
        ACCUM(p, v)
    }
#undef ACCUM
    float4 iv = *(const float4*)&inv[wid * 4];
    short* yp = Y + (size_t)wid * 256 + l;
    yp[0]   = f2bf(a0 * iv.x);
    yp[64]  = f2bf(a1 * iv.y);
    yp[128] = f2bf(a2 * iv.z);
    yp[192] = f2bf(a3 * iv.w);
}

// ---- MFMA GEMM K=320: out[n,:] = relu([Xb[n] | Y[n]] @ Wstack + bias), bf16 out ----
__global__ __launch_bounds__(256) void gemm_mfma_kernel(const short* __restrict__ Xb,
                                                        const short* __restrict__ Y,
                                                        const short* __restrict__ Wt,  // [c*320+k]
                                                        const float* __restrict__ bias,
                                                        short* __restrict__ out, int n) {
    __shared__ short sW[64 * 328];  // stride 328 to de-conflict banks
    const int t = threadIdx.x;
    for (int i = t; i < 64 * KK; i += 256) {
        int c = i / KK, k = i - c * KK;
        sW[c * 328 + k] = Wt[i];
    }
    const int wv = t >> 6;
    const int l = t & 63;
    const int m = l & 15;
    const int quad = l >> 4;
    const int node = blockIdx.x * 64 + wv * 16 + m;
    const bool valid = node < n;

    frag_ab a[10];
#pragma unroll
    for (int f = 0; f < 10; ++f) a[f] = frag_ab{};
    if (valid) {
        const short* xr = Xb + (size_t)node * 64 + quad * 8;
        a[0] = *(const frag_ab*)xr;
        a[1] = *(const frag_ab*)(xr + 32);
        const short* yr = Y + (size_t)node * 256 + quad * 8;
#pragma unroll
        for (int f = 0; f < 8; ++f) a[2 + f] = *(const frag_ab*)(yr + f * 32);
    }
    __syncthreads();

    const int nrow_base = blockIdx.x * 64 + wv * 16 + quad * 4;
#pragma unroll
    for (int ct = 0; ct < 4; ++ct) {
        const short* bp = sW + (ct * 16 + m) * 328 + quad * 8;
        frag_cd acc = {0.f, 0.f, 0.f, 0.f};
#pragma unroll
        for (int f = 0; f < 10; ++f) {
            frag_ab bf = *(const frag_ab*)(bp + f * 32);
            acc = __builtin_amdgcn_mfma_f32_16x16x32_bf16(a[f], bf, acc, 0, 0, 0);
        }
        int col = ct * 16 + m;
        float bv = bias[col];
#pragma unroll
        for (int r = 0; r < 4; ++r) {
            int nr = nrow_base + r;
            if (nr < n) out[(size_t)nr * 64 + col] = f2bf(fmaxf(acc[r] + bv, 0.f));
        }
    }
}

// ---- pool (segmented) + classifier ----
__global__ __launch_bounds__(256) void pool_cls_kernel(const short* __restrict__ h2,
                                                       const int* __restrict__ gstart,
                                                       const float* __restrict__ w,
                                                       const float* __restrict__ b,
                                                       float* __restrict__ out) {
    __shared__ float red[4][64];
    const int g = blockIdx.x;
    const int t = threadIdx.x;
    const int h = t & 63;
    const int wv = t >> 6;
    const int s = gstart[g], e = gstart[g + 1];

    float acc = 0.f;
    for (int i = s + wv; i < e; i += 4) acc += bf2f(h2[(size_t)i * 64 + h]);
    red[wv][h] = acc;
    __syncthreads();
    if (wv == 0) {
        float sum = red[0][h] + red[1][h] + red[2][h] + red[3][h];
        red[0][h] = sum / fmaxf((float)(e - s), 1.0f);
    }
    __syncthreads();
    if (t < 4) {
        float sres = 0.f;
#pragma unroll 8
        for (int hh = 0; hh < 64; ++hh) sres += red[0][hh] * w[hh * 4 + t];
        out[g * 4 + t] = sres + b[t];
    }
}

extern "C" void kernel_launch(void* const* d_in, const int* in_sizes, int n_in,
                              void* d_out, int out_size, void* d_ws, size_t ws_size,
                              hipStream_t stream) {
    const float* x        = (const float*)d_in[0];
    const int* edge_index = (const int*)d_in[1];
    const int* edge_type  = (const int*)d_in[2];
    const int* batch      = (const int*)d_in[3];
    const float* basis1 = (const float*)d_in[4];
    const float* comp1  = (const float*)d_in[5];
    const float* root1  = (const float*)d_in[6];
    const float* bias1  = (const float*)d_in[7];
    const float* basis2 = (const float*)d_in[8];
    const float* comp2  = (const float*)d_in[9];
    const float* root2  = (const float*)d_in[10];
    const float* bias2  = (const float*)d_in[11];
    const float* clas_w = (const float*)d_in[12];
    const float* clas_b = (const float*)d_in[13];

    const int N = in_sizes[0] / 64;
    const int E = in_sizes[2];
    const int G = out_size / 4;
    const int* src = edge_index;
    const int* dst = edge_index + E;
    const int NBUCK = (N + 255) >> 8;

    char* base = (char*)d_ws;
    size_t off = 0;
    auto carve = [&](size_t bytes) { void* p = base + off; off = (off + bytes + 15) & ~(size_t)15; return p; };
    int*   bcnt    = (int*)carve(sizeof(int) * 256);
    int*   cur0    = (int*)carve(sizeof(int) * 256);
    int*   row_ptr = (int*)carve(sizeof(int) * ((size_t)N + 1));
    int*   gstart  = (int*)carve(sizeof(int) * ((size_t)G + 1));
    int*   eidx    = (int*)carve(sizeof(int) * (size_t)E);
    int*   tmp     = (int*)carve(sizeof(int) * (size_t)E);
    float* inv     = (float*)carve(sizeof(float) * (size_t)N * RR);
    short* W1t     = (short*)carve(sizeof(short) * LWN);
    short* W2t     = (short*)carve(sizeof(short) * LWN);
    short* Xb1     = (short*)carve(sizeof(short) * (size_t)N * 64);
    short* H1      = (short*)carve(sizeof(short) * (size_t)N * 64);
    short* H2      = (short*)carve(sizeof(short) * (size_t)N * 64);
    short* Y       = (short*)carve(sizeof(short) * (size_t)N * 256);

    const int nb  = (N + 255) / 256;
    const int ebl = (E + EPB - 1) / EPB;
    const int wbl = (2 * LWN + 255) / 256;
    const int cvb = (N * 64 / 4 + 255) / 256;
    const int prep_blocks = ebl + wbl + nb + cvb;

    hipMemsetAsync(bcnt, 0, sizeof(int) * 512, stream);  // bcnt + cur0

    prep_kernel<<<prep_blocks, 256, 0, stream>>>(
        dst, E, NBUCK, bcnt,
        basis1, comp1, root1, basis2, comp2, root2, W1t, W2t,
        batch, gstart, N, G, row_ptr, x, Xb1, ebl, wbl, nb);
    bin_kernel<<<ebl, 256, 0, stream>>>(src, dst, edge_type, bcnt, cur0, tmp, E);
    csr_kernel<<<NBUCK, 256, 0, stream>>>(tmp, bcnt, row_ptr, eidx, inv, N);

    const int agg_blocks  = (N * 64 + 255) / 256;
    const int gemm_blocks = (N + 63) / 64;

    // layer 1
    agg_kernel<<<agg_blocks, 256, 0, stream>>>(row_ptr, eidx, Xb1, inv, Y, N);
    gemm_mfma_kernel<<<gemm_blocks, 256, 0, stream>>>(Xb1, Y, W1t, bias1, H1, N);

    // layer 2
    agg_kernel<<<agg_blocks, 256, 0, stream>>>(row_ptr, eidx, H1, inv, Y, N);
    gemm_mfma_kernel<<<gemm_blocks, 256, 0, stream>>>(H1, Y, W2t, bias2, H2, N);

    // pool + classifier
    pool_cls_kernel<<<G, 256, 0, stream>>>(H2, gstart, clas_w, clas_b, (float*)d_out);
}

// Round 10
// 227.059 us; speedup vs baseline: 1.3780x; 1.0562x over previous
//
#include <hip/hip_runtime.h>

// H2G2: 2-layer RGCN (R=4, per-relation mean) + mean-pool + linear.
// R1->R2: atomic scatter -> CSR gather. R2->R3: atomic pool -> segmented pool+cls.
// R3->R4: fp32 LDS GEMM -> bf16 MFMA. R4->R5: CSR via 2-level bucket sort.
// R5->R7: aggregate-then-transform; K=320 MFMA GEMM. R8 FAILED: Y-in-LDS fusion
//   capped occupancy (28%). R9: separate agg (8 gathers in flight) = 240us.
// R10: register-resident fusion. Lane (m,quad) owns exactly the 64 Y channels
//   its MFMA A-frag needs (16/relation); gather loads 2x16B per edge per lane
//   (4 lanes = full row) -> ~5x fewer VMEM instrs than R9 agg; Y never touches
//   LDS or global (51.2MB/layer killed); zero LDS -> no occupancy cap.
//   Needs eidx sorted by rel within node: csr now scans 1024 (dl,r) bins and
//   emits rp4[n] = int4 per-relation starts.

#define RR 4
#define HH 64
#define KK 320         // (RR+1)*HH
#define LWN (HH * KK)  // weights per layer = 20480
#define EPB 4096       // edges per binning block
#define SBUF_D 6144    // per-bucket staging cap

using frag_ab = __attribute__((ext_vector_type(8))) short;
using frag_cd = __attribute__((ext_vector_type(4))) float;

__device__ inline short f2bf(float f) {
    unsigned u = __builtin_bit_cast(unsigned, f);
    unsigned r = u + 0x7fffu + ((u >> 16) & 1u);  // RNE
    return (short)(r >> 16);
}
__device__ inline float bf2f(short s) {
    unsigned u = ((unsigned)(unsigned short)s) << 16;
    return __builtin_bit_cast(float, u);
}

// ---- prep: fused init-independent work, partitioned by blockIdx ----
__global__ __launch_bounds__(256) void prep_kernel(
    const int* __restrict__ dst, int E, int NBUCK, int* __restrict__ bcnt,
    const float* __restrict__ basis1, const float* __restrict__ comp1, const float* __restrict__ root1,
    const float* __restrict__ basis2, const float* __restrict__ comp2, const float* __restrict__ root2,
    short* __restrict__ W1t, short* __restrict__ W2t,
    const int* __restrict__ batch, int* __restrict__ gstart, int N, int G,
    int* __restrict__ row_ptr,
    const float* __restrict__ x, short* __restrict__ Xb,
    int ebl, int wbl, int nb) {
    const int bid = blockIdx.x;
    const int t = threadIdx.x;
    if (bid < ebl) {  // ---- histogram of dst>>8 ----
        __shared__ int lc[256];
        lc[t] = 0;
        __syncthreads();
        int e0 = bid * EPB, e1 = min(e0 + EPB, E);
        for (int e = e0 + t; e < e1; e += 256) atomicAdd(&lc[dst[e] >> 8], 1);
        __syncthreads();
        if (t < NBUCK && lc[t]) atomicAdd(&bcnt[t], lc[t]);
    } else if (bid < ebl + wbl) {  // ---- weights: Wt[c*320+k] = Wstack[k][c] ----
        int w = (bid - ebl) * 256 + t;
        int layer = w / LWN;
        int rem = w - layer * LWN;
        int c = rem / KK;
        int k = rem - c * KK;
        const float* basis = layer ? basis2 : basis1;
        const float* comp  = layer ? comp2  : comp1;
        const float* root  = layer ? root2  : root1;
        short* Wt          = layer ? W2t    : W1t;
        float v;
        if (k < HH) {
            v = root[k * HH + c];
        } else {
            int r = (k >> 6) - 1, kk = k & 63;
            v = 0.f;
#pragma unroll
            for (int b = 0; b < RR; ++b) v += comp[r * RR + b] * basis[(b * HH + kk) * HH + c];
        }
        Wt[c * KK + k] = f2bf(v);
    } else if (bid < ebl + wbl + nb) {  // ---- gstart + row_ptr sentinel ----
        int i = (bid - ebl - wbl) * 256 + t;
        if (i == 0) row_ptr[N] = E;
        if (i < N) {
            int b1 = batch[i];
            int b0 = (i == 0) ? -1 : batch[i - 1];
            for (int g = b0 + 1; g <= b1; ++g) gstart[g] = i;
            if (i == N - 1)
                for (int g = b1 + 1; g <= G; ++g) gstart[g] = N;
        }
    } else {  // ---- convert x fp32 -> bf16 ----
        int i4 = (bid - ebl - wbl - nb) * 256 + t;
        int base = i4 * 4;
        if (base < N * 64) {
            float4 f = *(const float4*)&x[base];
            short4 s;
            s.x = f2bf(f.x); s.y = f2bf(f.y); s.z = f2bf(f.z); s.w = f2bf(f.w);
            *(short4*)&Xb[base] = s;
        }
    }
}

// ---- bin: block-local counting sort by bucket; packed payload src:16|et:2|dl:8 ----
__global__ __launch_bounds__(256) void bin_kernel(const int* __restrict__ src,
                                                  const int* __restrict__ dst,
                                                  const int* __restrict__ et,
                                                  const int* __restrict__ bcnt,
                                                  int* __restrict__ cur0,
                                                  int* __restrict__ tmp, int E) {
    __shared__ int lc[256];
    __shared__ int lscan[257];
    __shared__ int lbase[256];
    __shared__ int ss[256];
    __shared__ int sbuf[EPB];
    int t = threadIdx.x;
    int bv = bcnt[t];
    ss[t] = bv;
    __syncthreads();
#pragma unroll
    for (int off = 1; off < 256; off <<= 1) {
        int u = (t >= off) ? ss[t - off] : 0;
        __syncthreads();
        ss[t] += u;
        __syncthreads();
    }
    int boff_t = ss[t] - bv;
    lc[t] = 0;
    __syncthreads();
    int e0 = blockIdx.x * EPB;
    int e1 = min(e0 + EPB, E);
    for (int e = e0 + t; e < e1; e += 256) atomicAdd(&lc[dst[e] >> 8], 1);
    __syncthreads();
    int v = lc[t];
    ss[t] = v;
    __syncthreads();
#pragma unroll
    for (int off = 1; off < 256; off <<= 1) {
        int u = (t >= off) ? ss[t - off] : 0;
        __syncthreads();
        ss[t] += u;
        __syncthreads();
    }
    lscan[t] = ss[t] - v;
    if (t == 255) lscan[256] = ss[255];
    if (v) lbase[t] = boff_t + atomicAdd(&cur0[t], v);
    lc[t] = 0;
    __syncthreads();
    for (int e = e0 + t; e < e1; e += 256) {
        int d = dst[e];
        int b = d >> 8;
        int p = (src[e] << 10) | (et[e] << 8) | (d & 255);
        int pos = lscan[b] + atomicAdd(&lc[b], 1);
        sbuf[pos] = p;
    }
    __syncthreads();
    int tot = lscan[256];
    for (int i = t; i < tot; i += 256) {
        int lo = 0, hi = 255;
        while (lo < hi) { int mid = (lo + hi + 1) >> 1; if (lscan[mid] <= i) lo = mid; else hi = mid - 1; }
        tmp[lbase[lo] + (i - lscan[lo])] = sbuf[i];
    }
}

// ---- csr: per-bucket finalize: row_ptr, rp4 (per-rel starts), inv,
//      eidx sorted by (dst, rel) ----
__global__ __launch_bounds__(256) void csr_kernel(const int* __restrict__ tmp,
                                                  const int* __restrict__ bcnt,
                                                  int* __restrict__ row_ptr,
                                                  int4* __restrict__ rp4,
                                                  int* __restrict__ eidx,
                                                  float* __restrict__ inv, int N) {
    __shared__ int cnt4l[1024];  // counts -> in-place per-(dl,r) start offsets/cursors
    __shared__ int dscan[256];
    __shared__ int ss[256];
    __shared__ int sb[SBUF_D];
    int b = blockIdx.x, t = threadIdx.x;
    int bv = bcnt[t];
    ss[t] = bv;
    __syncthreads();
#pragma unroll
    for (int off = 1; off < 256; off <<= 1) {
        int u = (t >= off) ? ss[t - off] : 0;
        __syncthreads();
        ss[t] += u;
        __syncthreads();
    }
    __shared__ int s0s, s1s;
    if (t == b) { s0s = ss[t] - bv; s1s = ss[t]; }
    __syncthreads();
    int s0 = s0s, s1 = s1s;
    int len = s1 - s0;
    for (int i = t; i < 1024; i += 256) cnt4l[i] = 0;
    __syncthreads();
    for (int i = s0 + t; i < s1; i += 256) {
        int e = tmp[i];
        atomicAdd(&cnt4l[((e & 255) << 2) | ((e >> 8) & 3)], 1);
    }
    __syncthreads();
    int c0 = cnt4l[t * 4], c1 = cnt4l[t * 4 + 1], c2 = cnt4l[t * 4 + 2], c3 = cnt4l[t * 4 + 3];
    int deg = c0 + c1 + c2 + c3;
    ss[t] = deg;
    __syncthreads();
#pragma unroll
    for (int off = 1; off < 256; off <<= 1) {
        int u = (t >= off) ? ss[t - off] : 0;
        __syncthreads();
        ss[t] += u;
        __syncthreads();
    }
    dscan[t] = ss[t] - deg;
    int d0 = b << 8;
    int d = d0 + t;
    // inv from raw counts
    if (d < N) {
        inv[d * 4 + 0] = 1.0f / fmaxf((float)c0, 1.0f);
        inv[d * 4 + 1] = 1.0f / fmaxf((float)c1, 1.0f);
        inv[d * 4 + 2] = 1.0f / fmaxf((float)c2, 1.0f);
        inv[d * 4 + 3] = 1.0f / fmaxf((float)c3, 1.0f);
    }
    // in-place convert cnt4l to per-(dl,r) start offsets (bucket-relative)
    int base = dscan[t];
    cnt4l[t * 4] = base;
    cnt4l[t * 4 + 1] = base + c0;
    cnt4l[t * 4 + 2] = base + c0 + c1;
    cnt4l[t * 4 + 3] = base + c0 + c1 + c2;
    if (d < N) {
        row_ptr[d] = s0 + base;
        rp4[d] = make_int4(s0 + base, s0 + base + c0, s0 + base + c0 + c1,
                           s0 + base + c0 + c1 + c2);
    }
    __syncthreads();
    if (len <= SBUF_D) {
        for (int i = s0 + t; i < s1; i += 256) {
            int e = tmp[i];
            int key = ((e & 255) << 2) | ((e >> 8) & 3);
            int pos = atomicAdd(&cnt4l[key], 1);  // cursor on start offsets
            sb[pos] = ((e >> 10) << 2) | ((e >> 8) & 3);  // (src<<2)|et
        }
        __syncthreads();
        for (int i = t; i < len; i += 256) eidx[s0 + i] = sb[i];
    } else {
        for (int i = s0 + t; i < s1; i += 256) {
            int e = tmp[i];
            int key = ((e & 255) << 2) | ((e >> 8) & 3);
            int pos = atomicAdd(&cnt4l[key], 1);
            eidx[s0 + pos] = ((e >> 10) << 2) | ((e >> 8) & 3);
        }
    }
}

// ---- fused layer: register-resident Y. Lane (m,quad) gathers 2x16B per edge
// (4 lanes cover the row), accumulating exactly its A-frag channels; then
// K=320 MFMA with B straight from global Wt. No LDS. ----
__global__ __launch_bounds__(256) void layer_kernel(const int* __restrict__ row_ptr,
                                                    const int4* __restrict__ rp4,
                                                    const int* __restrict__ eidx,
                                                    const short* __restrict__ Xb,
                                                    const float* __restrict__ inv,
                                                    const short* __restrict__ Wt,
                                                    const float* __restrict__ bias,
                                                    short* __restrict__ out, int n) {
    const int t = threadIdx.x;
    const int wv = t >> 6;
    const int l = t & 63;
    const int m = l & 15;
    const int quad = l >> 4;
    const int node = blockIdx.x * 64 + wv * 16 + m;
    const bool valid = node < n;

    float accL[4][8], accH[4][8];
#pragma unroll
    for (int r = 0; r < 4; ++r)
#pragma unroll
        for (int j = 0; j < 8; ++j) { accL[r][j] = 0.f; accH[r][j] = 0.f; }

    int4 r4 = make_int4(0, 0, 0, 0);
    int kend = 0;
    float4 iv = make_float4(0.f, 0.f, 0.f, 0.f);
    if (valid) {
        r4 = rp4[node];
        kend = row_ptr[node + 1];
        iv = *(const float4*)&inv[node * 4];
    }
    const short* xbq = Xb + quad * 8;

#define GATHER(RIDX, K0, K1)                                                  \
    {                                                                         \
        int k = (K0);                                                         \
        const int k1 = (K1);                                                  \
        for (; k + 1 < k1; k += 2) {                                          \
            int p0 = eidx[k], p1 = eidx[k + 1];                               \
            const short* a0p = xbq + (size_t)(p0 >> 2) * 64;                  \
            const short* a1p = xbq + (size_t)(p1 >> 2) * 64;                  \
            frag_ab x0l = *(const frag_ab*)a0p;                               \
            frag_ab x0h = *(const frag_ab*)(a0p + 32);                        \
            frag_ab x1l = *(const frag_ab*)a1p;                               \
            frag_ab x1h = *(const frag_ab*)(a1p + 32);                        \
            _Pragma("unroll") for (int j = 0; j < 8; ++j) {                   \
                accL[RIDX][j] += bf2f(x0l[j]) + bf2f(x1l[j]);                 \
                accH[RIDX][j] += bf2f(x0h[j]) + bf2f(x1h[j]);                 \
            }                                                                 \
        }                                                                     \
        if (k < k1) {                                                         \
            int p0 = eidx[k];                                                 \
            const short* a0p = xbq + (size_t)(p0 >> 2) * 64;                  \
            frag_ab x0l = *(const frag_ab*)a0p;                               \
            frag_ab x0h = *(const frag_ab*)(a0p + 32);                        \
            _Pragma("unroll") for (int j = 0; j < 8; ++j) {                   \
                accL[RIDX][j] += bf2f(x0l[j]);                                \
                accH[RIDX][j] += bf2f(x0h[j]);                                \
            }                                                                 \
        }                                                                     \
    }

    GATHER(0, r4.x, r4.y)
    GATHER(1, r4.y, r4.z)
    GATHER(2, r4.z, r4.w)
    GATHER(3, r4.w, kend)
#undef GATHER

    // build A-frags: a[0..1] = X row; a[2+2r], a[3+2r] = Y (scaled, bf16)
    frag_ab a[10];
#pragma unroll
    for (int f = 0; f < 10; ++f) a[f] = frag_ab{};
    if (valid) {
        const short* xr = Xb + (size_t)node * 64 + quad * 8;
        a[0] = *(const frag_ab*)xr;
        a[1] = *(const frag_ab*)(xr + 32);
    }
    {
        float s0 = iv.x, s1 = iv.y, s2 = iv.z, s3 = iv.w;
#pragma unroll
        for (int j = 0; j < 8; ++j) {
            a[2][j] = f2bf(accL[0][j] * s0); a[3][j] = f2bf(accH[0][j] * s0);
            a[4][j] = f2bf(accL[1][j] * s1); a[5][j] = f2bf(accH[1][j] * s1);
            a[6][j] = f2bf(accL[2][j] * s2); a[7][j] = f2bf(accH[2][j] * s2);
            a[8][j] = f2bf(accL[3][j] * s3); a[9][j] = f2bf(accH[3][j] * s3);
        }
    }

    const int nrow_base = blockIdx.x * 64 + wv * 16 + quad * 4;
#pragma unroll
    for (int ct = 0; ct < 4; ++ct) {
        const short* bp = Wt + (size_t)(ct * 16 + m) * KK + quad * 8;
        frag_cd acc = {0.f, 0.f, 0.f, 0.f};
#pragma unroll
        for (int f = 0; f < 10; ++f) {
            frag_ab bf = *(const frag_ab*)(bp + f * 32);
            acc = __builtin_amdgcn_mfma_f32_16x16x32_bf16(a[f], bf, acc, 0, 0, 0);
        }
        int col = ct * 16 + m;
        float bv = bias[col];
#pragma unroll
        for (int r = 0; r < 4; ++r) {
            int nr = nrow_base + r;
            if (nr < n) out[(size_t)nr * 64 + col] = f2bf(fmaxf(acc[r] + bv, 0.f));
        }
    }
}

// ---- pool (segmented) + classifier ----
__global__ __launch_bounds__(256) void pool_cls_kernel(const short* __restrict__ h2,
                                                       const int* __restrict__ gstart,
                                                       const float* __restrict__ w,
                                                       const float* __restrict__ b,
                                                       float* __restrict__ out) {
    __shared__ float red[4][64];
    const int g = blockIdx.x;
    const int t = threadIdx.x;
    const int h = t & 63;
    const int wv = t >> 6;
    const int s = gstart[g], e = gstart[g + 1];

    float acc = 0.f;
    for (int i = s + wv; i < e; i += 4) acc += bf2f(h2[(size_t)i * 64 + h]);
    red[wv][h] = acc;
    __syncthreads();
    if (wv == 0) {
        float sum = red[0][h] + red[1][h] + red[2][h] + red[3][h];
        red[0][h] = sum / fmaxf((float)(e - s), 1.0f);
    }
    __syncthreads();
    if (t < 4) {
        float sres = 0.f;
#pragma unroll 8
        for (int hh = 0; hh < 64; ++hh) sres += red[0][hh] * w[hh * 4 + t];
        out[g * 4 + t] = sres + b[t];
    }
}

extern "C" void kernel_launch(void* const* d_in, const int* in_sizes, int n_in,
                              void* d_out, int out_size, void* d_ws, size_t ws_size,
                              hipStream_t stream) {
    const float* x        = (const float*)d_in[0];
    const int* edge_index = (const int*)d_in[1];
    const int* edge_type  = (const int*)d_in[2];
    const int* batch      = (const int*)d_in[3];
    const float* basis1 = (const float*)d_in[4];
    const float* comp1  = (const float*)d_in[5];
    const float* root1  = (const float*)d_in[6];
    const float* bias1  = (const float*)d_in[7];
    const float* basis2 = (const float*)d_in[8];
    const float* comp2  = (const float*)d_in[9];
    const float* root2  = (const float*)d_in[10];
    const float* bias2  = (const float*)d_in[11];
    const float* clas_w = (const float*)d_in[12];
    const float* clas_b = (const float*)d_in[13];

    const int N = in_sizes[0] / 64;
    const int E = in_sizes[2];
    const int G = out_size / 4;
    const int* src = edge_index;
    const int* dst = edge_index + E;
    const int NBUCK = (N + 255) >> 8;

    char* base = (char*)d_ws;
    size_t off = 0;
    auto carve = [&](size_t bytes) { void* p = base + off; off = (off + bytes + 15) & ~(size_t)15; return p; };
    int*   bcnt    = (int*)carve(sizeof(int) * 256);
    int*   cur0    = (int*)carve(sizeof(int) * 256);
    int*   row_ptr = (int*)carve(sizeof(int) * ((size_t)N + 1));
    int4*  rp4     = (int4*)carve(sizeof(int4) * (size_t)N);
    int*   gstart  = (int*)carve(sizeof(int) * ((size_t)G + 1));
    int*   eidx    = (int*)carve(sizeof(int) * (size_t)E);
    int*   tmp     = (int*)carve(sizeof(int) * (size_t)E);
    float* inv     = (float*)carve(sizeof(float) * (size_t)N * RR);
    short* W1t     = (short*)carve(sizeof(short) * LWN);
    short* W2t     = (short*)carve(sizeof(short) * LWN);
    short* Xb1     = (short*)carve(sizeof(short) * (size_t)N * 64);
    short* H1      = (short*)carve(sizeof(short) * (size_t)N * 64);
    short* H2      = (short*)carve(sizeof(short) * (size_t)N * 64);

    const int nb  = (N + 255) / 256;
    const int ebl = (E + EPB - 1) / EPB;
    const int wbl = (2 * LWN + 255) / 256;
    const int cvb = (N * 64 / 4 + 255) / 256;
    const int prep_blocks = ebl + wbl + nb + cvb;

    hipMemsetAsync(bcnt, 0, sizeof(int) * 512, stream);  // bcnt + cur0

    prep_kernel<<<prep_blocks, 256, 0, stream>>>(
        dst, E, NBUCK, bcnt,
        basis1, comp1, root1, basis2, comp2, root2, W1t, W2t,
        batch, gstart, N, G, row_ptr, x, Xb1, ebl, wbl, nb);
    bin_kernel<<<ebl, 256, 0, stream>>>(src, dst, edge_type, bcnt, cur0, tmp, E);
    csr_kernel<<<NBUCK, 256, 0, stream>>>(tmp, bcnt, row_ptr, rp4, eidx, inv, N);

    const int layer_blocks = (N + 63) / 64;

    layer_kernel<<<layer_blocks, 256, 0, stream>>>(row_ptr, rp4, eidx, Xb1, inv, W1t, bias1, H1, N);
    layer_kernel<<<layer_blocks, 256, 0, stream>>>(row_ptr, rp4, eidx, H1, inv, W2t, bias2, H2, N);

    pool_cls_kernel<<<G, 256, 0, stream>>>(H2, gstart, clas_w, clas_b, (float*)d_out);
}